// Round 10
// baseline (187.743 us; speedup 1.0000x reference)
//
#include <hip/hip_runtime.h>
#include <stdint.h>

#define B_ 4
#define L_ 5
#define C_ 256
#define H_ 64
#define W_ 256
#define HW_ (H_ * W_)
#define IMGS_ (B_ * L_)
#define XT_BYTES ((size_t)IMGS_ * HW_ * C_ * 2)
#define NSTRIP_ 256                    // 64-px strips per image = HW/64
#define CNT_SLOTS_ (B_ * NSTRIP_)      // 1024 rate-count slots

typedef float f32x4 __attribute__((ext_vector_type(4)));

__device__ __forceinline__ uint32_t f2bf(float f) {
    uint32_t u = __float_as_uint(f);
    u += 0x7fffu + ((u >> 16) & 1u);   // round-to-nearest-even
    return u >> 16;
}
__device__ __forceinline__ float bf_lo(uint32_t p) { return __uint_as_float(p << 16); }
__device__ __forceinline__ float bf_hi(uint32_t p) { return __uint_as_float(p & 0xffff0000u); }

// ---------------- Phase 1: transpose + mask + bf16 quantize (+ rate slots) ----
// x (20,256,HW) fp32  ->  xt (20,HW,256) bf16, pre-multiplied by comm mask.
// (256,4): VGPR cap 128 vs ~48 live; R9 showed occupancy-neutral (BW-saturated).
// R10: plain loads (nt-load A/B — nt was never isolated; suspect it hurts streaming).
__global__ __launch_bounds__(256, 4)
void transpose_kernel(const float* __restrict__ x, const float* __restrict__ rm,
                      uint16_t* __restrict__ xt, int* __restrict__ cnt_arr)
{
    const int bl   = blockIdx.y;        // image 0..19
    const int pix0 = blockIdx.x * 64;   // 64-pixel strip
    const int b    = bl / L_;
    const bool use_mask = (b & 1) != 0; // reproduced masks_flat[b] indexing bug

    __shared__ __align__(16) uint16_t tile[64 * 264]; // [px][c], row = 132 words
    __shared__ float mval[64];

    const int tid = threadIdx.x;
    if (tid < 64) {
        float m = 1.f;
        if (use_mask) {
            float a0 = rm[(size_t)(b * 2 + 0) * HW_ + pix0 + tid];
            float a1 = rm[(size_t)(b * 2 + 1) * HW_ + pix0 + tid];
            m = (fmaxf(a0, a1) > 0.f) ? 1.f : 0.f;  // sigmoid(v)>0.5 <=> v>0
        }
        mval[tid] = m;
        // rate count: ego images (bl = b*L); every slot rewritten each call
        if (bl % L_ == 0) {
            const float r0 = rm[(size_t)(bl * 2 + 0) * HW_ + pix0 + tid];
            const float r1 = rm[(size_t)(bl * 2 + 1) * HW_ + pix0 + tid];
            const unsigned long long mb = __ballot(fmaxf(r0, r1) > 0.f);
            if (tid == 0) cnt_arr[(bl / L_) * NSTRIP_ + blockIdx.x] = (int)__popcll(mb);
        }
    }
    __syncthreads();

    const int i16   = tid & 15;         // pixel group (4 consecutive pixels)
    const int tpx   = i16 * 4;
    const int crow2 = tid >> 4;         // 0..15 -> channel pair base
    const float* __restrict__ src = x + (size_t)bl * C_ * HW_ + pix0;
    const float m0 = mval[tpx + 0], m1 = mval[tpx + 1];
    const float m2 = mval[tpx + 2], m3 = mval[tpx + 3];
    uint32_t* t32 = (uint32_t*)tile;
    const int wkey = (i16 & 7) << 2;    // swizzle key, same for px rows tpx..tpx+3

    #pragma unroll
    for (int pass = 0; pass < 8; ++pass) {
        const int c = pass * 32 + crow2 * 2;
        const f32x4 v0 = *reinterpret_cast<const f32x4*>(src + (size_t)c * HW_ + tpx);
        const f32x4 v1 = *reinterpret_cast<const f32x4*>(src + (size_t)(c + 1) * HW_ + tpx);
        const int wbs = (pass * 16 + crow2) ^ wkey;  // swizzled word index 0..127
        t32[(tpx + 0) * 132 + wbs] = f2bf(v0.x * m0) | (f2bf(v1.x * m0) << 16);
        t32[(tpx + 1) * 132 + wbs] = f2bf(v0.y * m1) | (f2bf(v1.y * m1) << 16);
        t32[(tpx + 2) * 132 + wbs] = f2bf(v0.z * m2) | (f2bf(v1.z * m2) << 16);
        t32[(tpx + 3) * 132 + wbs] = f2bf(v0.w * m3) | (f2bf(v1.w * m3) << 16);
    }
    __syncthreads();

    const int cth = tid & 31;           // 8 channels each
    const int pxw = tid >> 5;           // 0..7
    uint16_t* __restrict__ dst = xt + ((size_t)bl * HW_ + pix0) * C_;
    #pragma unroll
    for (int pass = 0; pass < 8; ++pass) {
        const int px   = pass * 8 + pxw;
        const int rkey = ((px >> 2) & 7) << 2;
        const uint4 d = *(const uint4*)&t32[px * 132 + ((cth * 4) ^ rkey)];
        *(uint4*)(dst + (size_t)px * C_ + cth * 8) = d;  // 512B rows, coalesced
    }
}

// ---------------- Phase 2: fused warp-gather + attention fusion + rate ----------------
// 1D grid 4096, XCD-swizzled so each XCD owns a contiguous 32-row slab of one b.
// (512,2): VGPR cap 256 — live use ~130-160, MUST NOT cap at 128 (R8: spills, +68us).
__global__ __launch_bounds__(512, 2)
void fuse_kernel(const uint16_t* __restrict__ xt, const float* __restrict__ Tmat,
                 float* __restrict__ out, const int* __restrict__ cnt_arr)
{
    // kernel-scope shared: statically co-allocated, no lifetime overlay (R5 lesson)
    __shared__ float obuf[16][257];
    __shared__ int   rsum[8];

    const int bid = blockIdx.x;                    // 0..4095
    const int swz = (bid & 7) * 512 + (bid >> 3);  // bijective XCD chunking
    const int wt  = swz & 15;
    const int h   = (swz >> 4) & 63;
    const int b   = swz >> 10;

    const int tid = threadIdx.x;
    const int cth = tid & 31;          // channel thread: c0 = cth*8
    const int px  = tid >> 5;          // 0..15
    const int w   = wt * 16 + px;

    const float gx = -1.0f + (2.0f * (float)w) / (float)(W_ - 1);
    const float gy = -1.0f + (2.0f * (float)h) / (float)(H_ - 1);

    float warped[L_][8];

    #pragma unroll
    for (int l = 0; l < L_; ++l) {
        const float* P = Tmat + ((size_t)(b * L_ + 0) * L_ + l) * 16;
        const float M00 = P[0];
        const float M01 = P[1] * ((float)H_ / (float)W_);
        const float M02 = P[3] * (2.0f / (4.0f * 0.4f * (float)W_));
        const float M10 = P[4] * ((float)W_ / (float)H_);
        const float M11 = P[5];
        const float M12 = P[7] * (2.0f / (4.0f * 0.4f * (float)H_));

        const float xs = (M00 * gx + M01 * gy + M02 + 1.0f) * 0.5f * (float)(W_ - 1);
        const float ys = (M10 * gx + M11 * gy + M12 + 1.0f) * 0.5f * (float)(H_ - 1);
        const float x0f = floorf(xs), y0f = floorf(ys);
        const float wx1 = xs - x0f, wx0 = 1.0f - wx1;
        const float wy1 = ys - y0f, wy0 = 1.0f - wy1;
        const int x0 = (int)x0f, y0 = (int)y0f;
        const int x1 = x0 + 1,  y1 = y0 + 1;
        const bool vx0 = (x0 >= 0) && (x0 < W_);
        const bool vx1 = (x1 >= 0) && (x1 < W_);
        const bool vy0 = (y0 >= 0) && (y0 < H_);
        const bool vy1 = (y1 >= 0) && (y1 < H_);
        const int x0c = min(max(x0, 0), W_ - 1);
        const int x1c = min(max(x1, 0), W_ - 1);
        const int y0c = min(max(y0, 0), H_ - 1);
        const int y1c = min(max(y1, 0), H_ - 1);

        const float w00 = wx0 * wy0 * ((vx0 && vy0) ? 1.f : 0.f);
        const float w01 = wx1 * wy0 * ((vx1 && vy0) ? 1.f : 0.f);
        const float w10 = wx0 * wy1 * ((vx0 && vy1) ? 1.f : 0.f);
        const float w11 = wx1 * wy1 * ((vx1 && vy1) ? 1.f : 0.f);

        const uint16_t* __restrict__ img = xt + (size_t)(b * L_ + l) * HW_ * C_ + cth * 8;
        const uint4 v00 = *(const uint4*)(img + (size_t)(y0c * W_ + x0c) * C_);
        const uint4 v01 = *(const uint4*)(img + (size_t)(y0c * W_ + x1c) * C_);
        const uint4 v10 = *(const uint4*)(img + (size_t)(y1c * W_ + x0c) * C_);
        const uint4 v11 = *(const uint4*)(img + (size_t)(y1c * W_ + x1c) * C_);

        const uint32_t a00[4] = {v00.x, v00.y, v00.z, v00.w};
        const uint32_t a01[4] = {v01.x, v01.y, v01.z, v01.w};
        const uint32_t a10[4] = {v10.x, v10.y, v10.z, v10.w};
        const uint32_t a11[4] = {v11.x, v11.y, v11.z, v11.w};
        #pragma unroll
        for (int q = 0; q < 4; ++q) {
            warped[l][2 * q + 0] = w00 * bf_lo(a00[q]) + w01 * bf_lo(a01[q])
                                 + w10 * bf_lo(a10[q]) + w11 * bf_lo(a11[q]);
            warped[l][2 * q + 1] = w00 * bf_hi(a00[q]) + w01 * bf_hi(a01[q])
                                 + w10 * bf_hi(a10[q]) + w11 * bf_hi(a11[q]);
        }
    }

    // per-pixel dot products (reduce over the 32 lanes sharing this pixel)
    float s[L_];
    #pragma unroll
    for (int m = 0; m < L_; ++m) {
        float acc = 0.f;
        #pragma unroll
        for (int j = 0; j < 8; ++j) acc += warped[0][j] * warped[m][j];
        s[m] = acc;
    }
    #pragma unroll
    for (int m = 0; m < L_; ++m) {
        s[m] += __shfl_xor(s[m], 1, 64);
        s[m] += __shfl_xor(s[m], 2, 64);
        s[m] += __shfl_xor(s[m], 4, 64);
        s[m] += __shfl_xor(s[m], 8, 64);
        s[m] += __shfl_xor(s[m], 16, 64);
    }

    float mx = s[0];
    #pragma unroll
    for (int m = 1; m < L_; ++m) mx = fmaxf(mx, s[m]);
    float a[L_];
    float sum = 0.f;
    #pragma unroll
    for (int m = 0; m < L_; ++m) { a[m] = __expf((s[m] - mx) * 0.0625f); sum += a[m]; }
    const float inv = 1.0f / sum;
    #pragma unroll
    for (int m = 0; m < L_; ++m) a[m] *= inv;

    #pragma unroll
    for (int j = 0; j < 8; ++j) {
        float o = 0.f;
        #pragma unroll
        for (int m = 0; m < L_; ++m) o += a[m] * warped[m][j];
        obuf[px][cth * 8 + j] = o;
    }
    __syncthreads();

    float* __restrict__ op = out + (size_t)b * C_ * HW_ + (size_t)h * W_ + wt * 16;
    #pragma unroll
    for (int k = 0; k < 8; ++k) {
        const int f  = tid + k * 512;
        const int c  = f >> 4;
        const int p2 = f & 15;
        __builtin_nontemporal_store(obuf[p2][c], op + (size_t)c * HW_ + p2);
    }

    // rate finalize (block 0 only; block-uniform branch, rsum disjoint from obuf)
    if (bid == 0) {
        __syncthreads();   // all obuf reads done before any rsum activity
        int v = cnt_arr[tid] + cnt_arr[tid + 512];
        #pragma unroll
        for (int off = 1; off < 64; off <<= 1) v += __shfl_xor(v, off, 64);
        if ((tid & 63) == 0) rsum[tid >> 6] = v;
        __syncthreads();
        if (tid == 0) {
            int total = 0;
            #pragma unroll
            for (int i = 0; i < 8; ++i) total += rsum[i];
            out[(size_t)B_ * C_ * HW_] = (float)total / (float)(B_ * HW_);
        }
    }
}

// ---------------- rate (fallback path only) ----------------
__global__ __launch_bounds__(1024)
void rate_kernel(const float* __restrict__ rm, float* __restrict__ out_rate)
{
    const int tid = threadIdx.x;
    int cnt = 0;
    for (int b = 0; b < B_; ++b) {
        const float4* __restrict__ r0 = (const float4*)(rm + (size_t)(b * L_) * 2 * HW_);
        const float4* __restrict__ r1 = (const float4*)(rm + (size_t)(b * L_) * 2 * HW_ + HW_);
        for (int i = tid; i < HW_ / 4; i += 1024) {
            const float4 u = r0[i], v = r1[i];
            cnt += (fmaxf(u.x, v.x) > 0.f) ? 1 : 0;
            cnt += (fmaxf(u.y, v.y) > 0.f) ? 1 : 0;
            cnt += (fmaxf(u.z, v.z) > 0.f) ? 1 : 0;
            cnt += (fmaxf(u.w, v.w) > 0.f) ? 1 : 0;
        }
    }
    #pragma unroll
    for (int off = 1; off < 64; off <<= 1) cnt += __shfl_xor(cnt, off, 64);
    __shared__ int red[16];
    if ((tid & 63) == 0) red[tid >> 6] = cnt;
    __syncthreads();
    if (tid == 0) {
        int total = 0;
        #pragma unroll
        for (int i = 0; i < 16; ++i) total += red[i];
        out_rate[0] = (float)total / (float)(B_ * HW_);
    }
}

// ---------------- fallback (monolithic, no workspace) ----------------
__global__ __launch_bounds__(256, 2)
void fused_fallback_kernel(const float* __restrict__ x, const float* __restrict__ rm,
                           const float* __restrict__ Tmat, float* __restrict__ out)
{
    const int tid = threadIdx.x;
    const int p   = tid & 15;
    const int cg  = tid >> 4;
    const int wt  = blockIdx.x;
    const int h   = blockIdx.y;
    const int b   = blockIdx.z;
    const int w   = wt * 16 + p;

    const float gx = -1.0f + (2.0f * (float)w) / (float)(W_ - 1);
    const float gy = -1.0f + (2.0f * (float)h) / (float)(H_ - 1);
    const bool use_mask = (b & 1) != 0;
    const float* __restrict__ mk0 = rm + (size_t)(b * 2 + 0) * HW_;
    const float* __restrict__ mk1 = rm + (size_t)(b * 2 + 1) * HW_;

    float vals[L_][16];
    #pragma unroll
    for (int l = 0; l < L_; ++l) {
        const float* P = Tmat + ((size_t)(b * L_ + 0) * L_ + l) * 16;
        const float M00 = P[0];
        const float M01 = P[1] * ((float)H_ / (float)W_);
        const float M02 = P[3] * (2.0f / (4.0f * 0.4f * (float)W_));
        const float M10 = P[4] * ((float)W_ / (float)H_);
        const float M11 = P[5];
        const float M12 = P[7] * (2.0f / (4.0f * 0.4f * (float)H_));
        const float xs = (M00 * gx + M01 * gy + M02 + 1.0f) * 0.5f * (float)(W_ - 1);
        const float ys = (M10 * gx + M11 * gy + M12 + 1.0f) * 0.5f * (float)(H_ - 1);
        const float x0f = floorf(xs), y0f = floorf(ys);
        const float wx1 = xs - x0f, wx0 = 1.0f - wx1;
        const float wy1 = ys - y0f, wy0 = 1.0f - wy1;
        const int x0 = (int)x0f, y0 = (int)y0f;
        const int x1 = x0 + 1,  y1 = y0 + 1;
        const bool vx0 = (x0 >= 0) && (x0 < W_);
        const bool vx1 = (x1 >= 0) && (x1 < W_);
        const bool vy0 = (y0 >= 0) && (y0 < H_);
        const bool vy1 = (y1 >= 0) && (y1 < H_);
        const int x0c = min(max(x0, 0), W_ - 1);
        const int x1c = min(max(x1, 0), W_ - 1);
        const int y0c = min(max(y0, 0), H_ - 1);
        const int y1c = min(max(y1, 0), H_ - 1);
        float m00 = 1.f, m01 = 1.f, m10 = 1.f, m11 = 1.f;
        if (use_mask) {
            m00 = (fmaxf(mk0[y0c * W_ + x0c], mk1[y0c * W_ + x0c]) > 0.f) ? 1.f : 0.f;
            m01 = (fmaxf(mk0[y0c * W_ + x1c], mk1[y0c * W_ + x1c]) > 0.f) ? 1.f : 0.f;
            m10 = (fmaxf(mk0[y1c * W_ + x0c], mk1[y1c * W_ + x0c]) > 0.f) ? 1.f : 0.f;
            m11 = (fmaxf(mk0[y1c * W_ + x1c], mk1[y1c * W_ + x1c]) > 0.f) ? 1.f : 0.f;
        }
        const float w00 = wx0 * wy0 * ((vx0 && vy0) ? m00 : 0.f);
        const float w01 = wx1 * wy0 * ((vx1 && vy0) ? m01 : 0.f);
        const float w10 = wx0 * wy1 * ((vx0 && vy1) ? m10 : 0.f);
        const float w11 = wx1 * wy1 * ((vx1 && vy1) ? m11 : 0.f);
        const float* __restrict__ img = x + ((size_t)(b * L_ + l) * C_ + (size_t)cg * 16) * HW_;
        const float* __restrict__ r0 = img + (size_t)y0c * W_;
        const float* __restrict__ r1 = img + (size_t)y1c * W_;
        #pragma unroll
        for (int j = 0; j < 16; ++j) {
            vals[l][j] = w00 * r0[(size_t)j * HW_ + x0c] + w01 * r0[(size_t)j * HW_ + x1c]
                       + w10 * r1[(size_t)j * HW_ + x0c] + w11 * r1[(size_t)j * HW_ + x1c];
        }
    }
    float s[L_];
    #pragma unroll
    for (int m = 0; m < L_; ++m) {
        float acc = 0.f;
        #pragma unroll
        for (int j = 0; j < 16; ++j) acc += vals[0][j] * vals[m][j];
        s[m] = acc;
    }
    #pragma unroll
    for (int m = 0; m < L_; ++m) {
        s[m] += __shfl_xor(s[m], 16, 64);
        s[m] += __shfl_xor(s[m], 32, 64);
    }
    __shared__ float part[4][16][L_];
    __shared__ float attn[16][L_];
    const int wave = tid >> 6, lane = tid & 63;
    if (lane < 16) {
        #pragma unroll
        for (int m = 0; m < L_; ++m) part[wave][lane][m] = s[m];
    }
    __syncthreads();
    if (tid < 16) {
        float d[L_];
        #pragma unroll
        for (int m = 0; m < L_; ++m)
            d[m] = part[0][tid][m] + part[1][tid][m] + part[2][tid][m] + part[3][tid][m];
        float mx = d[0];
        #pragma unroll
        for (int m = 1; m < L_; ++m) mx = fmaxf(mx, d[m]);
        float e[L_]; float sum = 0.f;
        #pragma unroll
        for (int m = 0; m < L_; ++m) { e[m] = __expf((d[m] - mx) * 0.0625f); sum += e[m]; }
        const float inv = 1.0f / sum;
        #pragma unroll
        for (int m = 0; m < L_; ++m) attn[tid][m] = e[m] * inv;
    }
    __syncthreads();
    float a[L_];
    #pragma unroll
    for (int m = 0; m < L_; ++m) a[m] = attn[p][m];
    float* __restrict__ op = out + (((size_t)b * C_ + (size_t)cg * 16) * H_ + h) * W_ + (size_t)wt * 16 + p;
    #pragma unroll
    for (int j = 0; j < 16; ++j) {
        float o = 0.f;
        #pragma unroll
        for (int m = 0; m < L_; ++m) o += a[m] * vals[m][j];
        op[(size_t)j * HW_] = o;
    }
}

extern "C" void kernel_launch(void* const* d_in, const int* in_sizes, int n_in,
                              void* d_out, int out_size, void* d_ws, size_t ws_size,
                              hipStream_t stream) {
    const float* x  = (const float*)d_in[0];
    const float* rm = (const float*)d_in[1];
    const float* T  = (const float*)d_in[3];
    float* out = (float*)d_out;

    if (ws_size >= XT_BYTES + CNT_SLOTS_ * sizeof(int)) {
        uint16_t* xt = (uint16_t*)d_ws;
        int* cnt_arr = (int*)((char*)d_ws + XT_BYTES);
        dim3 tgrid(NSTRIP_, IMGS_);
        transpose_kernel<<<tgrid, 256, 0, stream>>>(x, rm, xt, cnt_arr);
        fuse_kernel<<<dim3(4096), 512, 0, stream>>>(xt, T, out, cnt_arr);
    } else {
        dim3 fgrid(W_ / 16, H_, B_);
        fused_fallback_kernel<<<fgrid, 256, 0, stream>>>(x, rm, T, out);
        rate_kernel<<<1, 1024, 0, stream>>>(rm, out + (size_t)B_ * C_ * HW_);
    }
}

// Round 11
// 151.029 us; speedup vs baseline: 1.2431x; 1.2431x over previous
//
#include <hip/hip_runtime.h>
#include <stdint.h>

#define B_ 4
#define L_ 5
#define C_ 256
#define H_ 64
#define W_ 256
#define HW_ (H_ * W_)
#define IMGS_ (B_ * L_)
#define XT_BYTES ((size_t)IMGS_ * HW_ * C_ * 2)
#define NSTRIP_ 256                    // 64-px strips per image = HW/64
#define CNT_SLOTS_ (B_ * NSTRIP_)      // 1024 rate-count slots

typedef float f32x4 __attribute__((ext_vector_type(4)));

__device__ __forceinline__ uint32_t f2bf(float f) {
    uint32_t u = __float_as_uint(f);
    u += 0x7fffu + ((u >> 16) & 1u);   // round-to-nearest-even
    return u >> 16;
}
__device__ __forceinline__ float bf_lo(uint32_t p) { return __uint_as_float(p << 16); }
__device__ __forceinline__ float bf_hi(uint32_t p) { return __uint_as_float(p & 0xffff0000u); }

// ---------------- Phase 1: transpose + mask + bf16 quantize (+ rate slots) ----
// x (20,256,HW) fp32  ->  xt (20,HW,256) bf16, pre-multiplied by comm mask.
// NT LOADS ARE LOAD-BEARING (R10 A/B: removing them = +34us). x is a 335MB
// read-once stream; nt keeps it from evicting the 168MB xt set from L3,
// so fuse's gathers stay L3-resident.
__global__ __launch_bounds__(256, 4)
void transpose_kernel(const float* __restrict__ x, const float* __restrict__ rm,
                      uint16_t* __restrict__ xt, int* __restrict__ cnt_arr)
{
    const int bl   = blockIdx.y;        // image 0..19
    const int pix0 = blockIdx.x * 64;   // 64-pixel strip
    const int b    = bl / L_;
    const bool use_mask = (b & 1) != 0; // reproduced masks_flat[b] indexing bug

    __shared__ __align__(16) uint16_t tile[64 * 264]; // [px][c], row = 132 words
    __shared__ float mval[64];

    const int tid = threadIdx.x;
    if (tid < 64) {
        float m = 1.f;
        if (use_mask) {
            float a0 = rm[(size_t)(b * 2 + 0) * HW_ + pix0 + tid];
            float a1 = rm[(size_t)(b * 2 + 1) * HW_ + pix0 + tid];
            m = (fmaxf(a0, a1) > 0.f) ? 1.f : 0.f;  // sigmoid(v)>0.5 <=> v>0
        }
        mval[tid] = m;
        // rate count: ego images (bl = b*L); every slot rewritten each call
        if (bl % L_ == 0) {
            const float r0 = rm[(size_t)(bl * 2 + 0) * HW_ + pix0 + tid];
            const float r1 = rm[(size_t)(bl * 2 + 1) * HW_ + pix0 + tid];
            const unsigned long long mb = __ballot(fmaxf(r0, r1) > 0.f);
            if (tid == 0) cnt_arr[(bl / L_) * NSTRIP_ + blockIdx.x] = (int)__popcll(mb);
        }
    }
    __syncthreads();

    const int i16   = tid & 15;         // pixel group (4 consecutive pixels)
    const int tpx   = i16 * 4;
    const int crow2 = tid >> 4;         // 0..15 -> channel pair base
    const float* __restrict__ src = x + (size_t)bl * C_ * HW_ + pix0;
    const float m0 = mval[tpx + 0], m1 = mval[tpx + 1];
    const float m2 = mval[tpx + 2], m3 = mval[tpx + 3];
    uint32_t* t32 = (uint32_t*)tile;
    const int wkey = (i16 & 7) << 2;    // swizzle key, same for px rows tpx..tpx+3

    #pragma unroll
    for (int pass = 0; pass < 8; ++pass) {
        const int c = pass * 32 + crow2 * 2;
        const f32x4 v0 = __builtin_nontemporal_load(
            reinterpret_cast<const f32x4*>(src + (size_t)c * HW_ + tpx));
        const f32x4 v1 = __builtin_nontemporal_load(
            reinterpret_cast<const f32x4*>(src + (size_t)(c + 1) * HW_ + tpx));
        const int wbs = (pass * 16 + crow2) ^ wkey;  // swizzled word index 0..127
        t32[(tpx + 0) * 132 + wbs] = f2bf(v0.x * m0) | (f2bf(v1.x * m0) << 16);
        t32[(tpx + 1) * 132 + wbs] = f2bf(v0.y * m1) | (f2bf(v1.y * m1) << 16);
        t32[(tpx + 2) * 132 + wbs] = f2bf(v0.z * m2) | (f2bf(v1.z * m2) << 16);
        t32[(tpx + 3) * 132 + wbs] = f2bf(v0.w * m3) | (f2bf(v1.w * m3) << 16);
    }
    __syncthreads();

    const int cth = tid & 31;           // 8 channels each
    const int pxw = tid >> 5;           // 0..7
    uint16_t* __restrict__ dst = xt + ((size_t)bl * HW_ + pix0) * C_;
    #pragma unroll
    for (int pass = 0; pass < 8; ++pass) {
        const int px   = pass * 8 + pxw;
        const int rkey = ((px >> 2) & 7) << 2;
        const uint4 d = *(const uint4*)&t32[px * 132 + ((cth * 4) ^ rkey)];
        *(uint4*)(dst + (size_t)px * C_ + cth * 8) = d;  // 512B rows, coalesced
    }
}

// ---------------- Phase 2: fused warp-gather + attention fusion + rate ----------------
// 1D grid 4096, XCD-swizzled so each XCD owns a contiguous 32-row slab of one b.
// (512,2): VGPR cap 256 — live use ~130-160, MUST NOT cap at 128 (R8: spills, +68us).
__global__ __launch_bounds__(512, 2)
void fuse_kernel(const uint16_t* __restrict__ xt, const float* __restrict__ Tmat,
                 float* __restrict__ out, const int* __restrict__ cnt_arr)
{
    // kernel-scope shared: statically co-allocated, no lifetime overlay (R5 lesson)
    __shared__ float obuf[16][257];
    __shared__ int   rsum[8];

    const int bid = blockIdx.x;                    // 0..4095
    const int swz = (bid & 7) * 512 + (bid >> 3);  // bijective XCD chunking
    const int wt  = swz & 15;
    const int h   = (swz >> 4) & 63;
    const int b   = swz >> 10;

    const int tid = threadIdx.x;
    const int cth = tid & 31;          // channel thread: c0 = cth*8
    const int px  = tid >> 5;          // 0..15
    const int w   = wt * 16 + px;

    const float gx = -1.0f + (2.0f * (float)w) / (float)(W_ - 1);
    const float gy = -1.0f + (2.0f * (float)h) / (float)(H_ - 1);

    float warped[L_][8];

    #pragma unroll
    for (int l = 0; l < L_; ++l) {
        const float* P = Tmat + ((size_t)(b * L_ + 0) * L_ + l) * 16;
        const float M00 = P[0];
        const float M01 = P[1] * ((float)H_ / (float)W_);
        const float M02 = P[3] * (2.0f / (4.0f * 0.4f * (float)W_));
        const float M10 = P[4] * ((float)W_ / (float)H_);
        const float M11 = P[5];
        const float M12 = P[7] * (2.0f / (4.0f * 0.4f * (float)H_));

        const float xs = (M00 * gx + M01 * gy + M02 + 1.0f) * 0.5f * (float)(W_ - 1);
        const float ys = (M10 * gx + M11 * gy + M12 + 1.0f) * 0.5f * (float)(H_ - 1);
        const float x0f = floorf(xs), y0f = floorf(ys);
        const float wx1 = xs - x0f, wx0 = 1.0f - wx1;
        const float wy1 = ys - y0f, wy0 = 1.0f - wy1;
        const int x0 = (int)x0f, y0 = (int)y0f;
        const int x1 = x0 + 1,  y1 = y0 + 1;
        const bool vx0 = (x0 >= 0) && (x0 < W_);
        const bool vx1 = (x1 >= 0) && (x1 < W_);
        const bool vy0 = (y0 >= 0) && (y0 < H_);
        const bool vy1 = (y1 >= 0) && (y1 < H_);
        const int x0c = min(max(x0, 0), W_ - 1);
        const int x1c = min(max(x1, 0), W_ - 1);
        const int y0c = min(max(y0, 0), H_ - 1);
        const int y1c = min(max(y1, 0), H_ - 1);

        const float w00 = wx0 * wy0 * ((vx0 && vy0) ? 1.f : 0.f);
        const float w01 = wx1 * wy0 * ((vx1 && vy0) ? 1.f : 0.f);
        const float w10 = wx0 * wy1 * ((vx0 && vy1) ? 1.f : 0.f);
        const float w11 = wx1 * wy1 * ((vx1 && vy1) ? 1.f : 0.f);

        const uint16_t* __restrict__ img = xt + (size_t)(b * L_ + l) * HW_ * C_ + cth * 8;
        const uint4 v00 = *(const uint4*)(img + (size_t)(y0c * W_ + x0c) * C_);
        const uint4 v01 = *(const uint4*)(img + (size_t)(y0c * W_ + x1c) * C_);
        const uint4 v10 = *(const uint4*)(img + (size_t)(y1c * W_ + x0c) * C_);
        const uint4 v11 = *(const uint4*)(img + (size_t)(y1c * W_ + x1c) * C_);

        const uint32_t a00[4] = {v00.x, v00.y, v00.z, v00.w};
        const uint32_t a01[4] = {v01.x, v01.y, v01.z, v01.w};
        const uint32_t a10[4] = {v10.x, v10.y, v10.z, v10.w};
        const uint32_t a11[4] = {v11.x, v11.y, v11.z, v11.w};
        #pragma unroll
        for (int q = 0; q < 4; ++q) {
            warped[l][2 * q + 0] = w00 * bf_lo(a00[q]) + w01 * bf_lo(a01[q])
                                 + w10 * bf_lo(a10[q]) + w11 * bf_lo(a11[q]);
            warped[l][2 * q + 1] = w00 * bf_hi(a00[q]) + w01 * bf_hi(a01[q])
                                 + w10 * bf_hi(a10[q]) + w11 * bf_hi(a11[q]);
        }
    }

    // per-pixel dot products (reduce over the 32 lanes sharing this pixel)
    float s[L_];
    #pragma unroll
    for (int m = 0; m < L_; ++m) {
        float acc = 0.f;
        #pragma unroll
        for (int j = 0; j < 8; ++j) acc += warped[0][j] * warped[m][j];
        s[m] = acc;
    }
    #pragma unroll
    for (int m = 0; m < L_; ++m) {
        s[m] += __shfl_xor(s[m], 1, 64);
        s[m] += __shfl_xor(s[m], 2, 64);
        s[m] += __shfl_xor(s[m], 4, 64);
        s[m] += __shfl_xor(s[m], 8, 64);
        s[m] += __shfl_xor(s[m], 16, 64);
    }

    float mx = s[0];
    #pragma unroll
    for (int m = 1; m < L_; ++m) mx = fmaxf(mx, s[m]);
    float a[L_];
    float sum = 0.f;
    #pragma unroll
    for (int m = 0; m < L_; ++m) { a[m] = __expf((s[m] - mx) * 0.0625f); sum += a[m]; }
    const float inv = 1.0f / sum;
    #pragma unroll
    for (int m = 0; m < L_; ++m) a[m] *= inv;

    #pragma unroll
    for (int j = 0; j < 8; ++j) {
        float o = 0.f;
        #pragma unroll
        for (int m = 0; m < L_; ++m) o += a[m] * warped[m][j];
        obuf[px][cth * 8 + j] = o;
    }
    __syncthreads();

    float* __restrict__ op = out + (size_t)b * C_ * HW_ + (size_t)h * W_ + wt * 16;
    #pragma unroll
    for (int k = 0; k < 8; ++k) {
        const int f  = tid + k * 512;
        const int c  = f >> 4;
        const int p2 = f & 15;
        __builtin_nontemporal_store(obuf[p2][c], op + (size_t)c * HW_ + p2);
    }

    // rate finalize (block 0 only; block-uniform branch, rsum disjoint from obuf)
    if (bid == 0) {
        __syncthreads();   // all obuf reads done before any rsum activity
        int v = cnt_arr[tid] + cnt_arr[tid + 512];
        #pragma unroll
        for (int off = 1; off < 64; off <<= 1) v += __shfl_xor(v, off, 64);
        if ((tid & 63) == 0) rsum[tid >> 6] = v;
        __syncthreads();
        if (tid == 0) {
            int total = 0;
            #pragma unroll
            for (int i = 0; i < 8; ++i) total += rsum[i];
            out[(size_t)B_ * C_ * HW_] = (float)total / (float)(B_ * HW_);
        }
    }
}

// ---------------- rate (fallback path only) ----------------
__global__ __launch_bounds__(1024)
void rate_kernel(const float* __restrict__ rm, float* __restrict__ out_rate)
{
    const int tid = threadIdx.x;
    int cnt = 0;
    for (int b = 0; b < B_; ++b) {
        const float4* __restrict__ r0 = (const float4*)(rm + (size_t)(b * L_) * 2 * HW_);
        const float4* __restrict__ r1 = (const float4*)(rm + (size_t)(b * L_) * 2 * HW_ + HW_);
        for (int i = tid; i < HW_ / 4; i += 1024) {
            const float4 u = r0[i], v = r1[i];
            cnt += (fmaxf(u.x, v.x) > 0.f) ? 1 : 0;
            cnt += (fmaxf(u.y, v.y) > 0.f) ? 1 : 0;
            cnt += (fmaxf(u.z, v.z) > 0.f) ? 1 : 0;
            cnt += (fmaxf(u.w, v.w) > 0.f) ? 1 : 0;
        }
    }
    #pragma unroll
    for (int off = 1; off < 64; off <<= 1) cnt += __shfl_xor(cnt, off, 64);
    __shared__ int red[16];
    if ((tid & 63) == 0) red[tid >> 6] = cnt;
    __syncthreads();
    if (tid == 0) {
        int total = 0;
        #pragma unroll
        for (int i = 0; i < 16; ++i) total += red[i];
        out_rate[0] = (float)total / (float)(B_ * HW_);
    }
}

// ---------------- fallback (monolithic, no workspace) ----------------
__global__ __launch_bounds__(256, 2)
void fused_fallback_kernel(const float* __restrict__ x, const float* __restrict__ rm,
                           const float* __restrict__ Tmat, float* __restrict__ out)
{
    const int tid = threadIdx.x;
    const int p   = tid & 15;
    const int cg  = tid >> 4;
    const int wt  = blockIdx.x;
    const int h   = blockIdx.y;
    const int b   = blockIdx.z;
    const int w   = wt * 16 + p;

    const float gx = -1.0f + (2.0f * (float)w) / (float)(W_ - 1);
    const float gy = -1.0f + (2.0f * (float)h) / (float)(H_ - 1);
    const bool use_mask = (b & 1) != 0;
    const float* __restrict__ mk0 = rm + (size_t)(b * 2 + 0) * HW_;
    const float* __restrict__ mk1 = rm + (size_t)(b * 2 + 1) * HW_;

    float vals[L_][16];
    #pragma unroll
    for (int l = 0; l < L_; ++l) {
        const float* P = Tmat + ((size_t)(b * L_ + 0) * L_ + l) * 16;
        const float M00 = P[0];
        const float M01 = P[1] * ((float)H_ / (float)W_);
        const float M02 = P[3] * (2.0f / (4.0f * 0.4f * (float)W_));
        const float M10 = P[4] * ((float)W_ / (float)H_);
        const float M11 = P[5];
        const float M12 = P[7] * (2.0f / (4.0f * 0.4f * (float)H_));
        const float xs = (M00 * gx + M01 * gy + M02 + 1.0f) * 0.5f * (float)(W_ - 1);
        const float ys = (M10 * gx + M11 * gy + M12 + 1.0f) * 0.5f * (float)(H_ - 1);
        const float x0f = floorf(xs), y0f = floorf(ys);
        const float wx1 = xs - x0f, wx0 = 1.0f - wx1;
        const float wy1 = ys - y0f, wy0 = 1.0f - wy1;
        const int x0 = (int)x0f, y0 = (int)y0f;
        const int x1 = x0 + 1,  y1 = y0 + 1;
        const bool vx0 = (x0 >= 0) && (x0 < W_);
        const bool vx1 = (x1 >= 0) && (x1 < W_);
        const bool vy0 = (y0 >= 0) && (y0 < H_);
        const bool vy1 = (y1 >= 0) && (y1 < H_);
        const int x0c = min(max(x0, 0), W_ - 1);
        const int x1c = min(max(x1, 0), W_ - 1);
        const int y0c = min(max(y0, 0), H_ - 1);
        const int y1c = min(max(y1, 0), H_ - 1);
        float m00 = 1.f, m01 = 1.f, m10 = 1.f, m11 = 1.f;
        if (use_mask) {
            m00 = (fmaxf(mk0[y0c * W_ + x0c], mk1[y0c * W_ + x0c]) > 0.f) ? 1.f : 0.f;
            m01 = (fmaxf(mk0[y0c * W_ + x1c], mk1[y0c * W_ + x1c]) > 0.f) ? 1.f : 0.f;
            m10 = (fmaxf(mk0[y1c * W_ + x0c], mk1[y1c * W_ + x0c]) > 0.f) ? 1.f : 0.f;
            m11 = (fmaxf(mk0[y1c * W_ + x1c], mk1[y1c * W_ + x1c]) > 0.f) ? 1.f : 0.f;
        }
        const float w00 = wx0 * wy0 * ((vx0 && vy0) ? m00 : 0.f);
        const float w01 = wx1 * wy0 * ((vx1 && vy0) ? m01 : 0.f);
        const float w10 = wx0 * wy1 * ((vx0 && vy1) ? m10 : 0.f);
        const float w11 = wx1 * wy1 * ((vx1 && vy1) ? m11 : 0.f);
        const float* __restrict__ img = x + ((size_t)(b * L_ + l) * C_ + (size_t)cg * 16) * HW_;
        const float* __restrict__ r0 = img + (size_t)y0c * W_;
        const float* __restrict__ r1 = img + (size_t)y1c * W_;
        #pragma unroll
        for (int j = 0; j < 16; ++j) {
            vals[l][j] = w00 * r0[(size_t)j * HW_ + x0c] + w01 * r0[(size_t)j * HW_ + x1c]
                       + w10 * r1[(size_t)j * HW_ + x0c] + w11 * r1[(size_t)j * HW_ + x1c];
        }
    }
    float s[L_];
    #pragma unroll
    for (int m = 0; m < L_; ++m) {
        float acc = 0.f;
        #pragma unroll
        for (int j = 0; j < 16; ++j) acc += vals[0][j] * vals[m][j];
        s[m] = acc;
    }
    #pragma unroll
    for (int m = 0; m < L_; ++m) {
        s[m] += __shfl_xor(s[m], 16, 64);
        s[m] += __shfl_xor(s[m], 32, 64);
    }
    __shared__ float part[4][16][L_];
    __shared__ float attn[16][L_];
    const int wave = tid >> 6, lane = tid & 63;
    if (lane < 16) {
        #pragma unroll
        for (int m = 0; m < L_; ++m) part[wave][lane][m] = s[m];
    }
    __syncthreads();
    if (tid < 16) {
        float d[L_];
        #pragma unroll
        for (int m = 0; m < L_; ++m)
            d[m] = part[0][tid][m] + part[1][tid][m] + part[2][tid][m] + part[3][tid][m];
        float mx = d[0];
        #pragma unroll
        for (int m = 1; m < L_; ++m) mx = fmaxf(mx, d[m]);
        float e[L_]; float sum = 0.f;
        #pragma unroll
        for (int m = 0; m < L_; ++m) { e[m] = __expf((d[m] - mx) * 0.0625f); sum += e[m]; }
        const float inv = 1.0f / sum;
        #pragma unroll
        for (int m = 0; m < L_; ++m) attn[tid][m] = e[m] * inv;
    }
    __syncthreads();
    float a[L_];
    #pragma unroll
    for (int m = 0; m < L_; ++m) a[m] = attn[p][m];
    float* __restrict__ op = out + (((size_t)b * C_ + (size_t)cg * 16) * H_ + h) * W_ + (size_t)wt * 16 + p;
    #pragma unroll
    for (int j = 0; j < 16; ++j) {
        float o = 0.f;
        #pragma unroll
        for (int m = 0; m < L_; ++m) o += a[m] * vals[m][j];
        op[(size_t)j * HW_] = o;
    }
}

extern "C" void kernel_launch(void* const* d_in, const int* in_sizes, int n_in,
                              void* d_out, int out_size, void* d_ws, size_t ws_size,
                              hipStream_t stream) {
    const float* x  = (const float*)d_in[0];
    const float* rm = (const float*)d_in[1];
    const float* T  = (const float*)d_in[3];
    float* out = (float*)d_out;

    if (ws_size >= XT_BYTES + CNT_SLOTS_ * sizeof(int)) {
        uint16_t* xt = (uint16_t*)d_ws;
        int* cnt_arr = (int*)((char*)d_ws + XT_BYTES);
        dim3 tgrid(NSTRIP_, IMGS_);
        transpose_kernel<<<tgrid, 256, 0, stream>>>(x, rm, xt, cnt_arr);
        fuse_kernel<<<dim3(4096), 512, 0, stream>>>(xt, T, out, cnt_arr);
    } else {
        dim3 fgrid(W_ / 16, H_, B_);
        fused_fallback_kernel<<<fgrid, 256, 0, stream>>>(x, rm, T, out);
        rate_kernel<<<1, 1024, 0, stream>>>(rm, out + (size_t)B_ * C_ * HW_);
    }
}